// Round 15
// baseline (419.186 us; speedup 1.0000x reference)
//
#include <hip/hip_runtime.h>

typedef unsigned short u16;
typedef unsigned int   u32;
typedef __attribute__((ext_vector_type(8))) __bf16 bf16x8;
typedef __attribute__((ext_vector_type(4))) float  f32x4;

#define BB   16
#define CH   256
#define HW   2304
#define SEQ  2048
#define EMB  256
#define CTXD 128
#define OUT0 9437184   // 16*256*2304, float offset of att region in d_out

#define MFMA(a,b,c) __builtin_amdgcn_mfma_f32_16x16x32_bf16(a,b,c,0,0,0)

__device__ __forceinline__ u16 f2bf(float f){
  u32 u = __builtin_bit_cast(u32, f);
  u += 0x7fffu + ((u >> 16) & 1u);
  return (u16)(u >> 16);
}
__device__ __forceinline__ float bf2f(u32 us){ return __builtin_bit_cast(float, us << 16); }

__device__ __forceinline__ bf16x8 ld16(const u16* p){
  uint4 q = *reinterpret_cast<const uint4*>(p);
  return __builtin_bit_cast(bf16x8, q);
}
__device__ __forceinline__ bf16x8 ld16c(const char* p){
  uint4 q = *reinterpret_cast<const uint4*>(p);
  return __builtin_bit_cast(bf16x8, q);
}
__device__ __forceinline__ bf16x8 mk8(float a0,float a1,float a2,float a3,
                                      float a4,float a5,float a6,float a7){
  uint4 q;
  q.x = (u32)f2bf(a0) | ((u32)f2bf(a1) << 16);
  q.y = (u32)f2bf(a2) | ((u32)f2bf(a3) << 16);
  q.z = (u32)f2bf(a4) | ((u32)f2bf(a5) << 16);
  q.w = (u32)f2bf(a6) | ((u32)f2bf(a7) << 16);
  return __builtin_bit_cast(bf16x8, q);
}
// async global->LDS, 16B per lane (dest linear: base + lane*16)
__device__ __forceinline__ void gload16(const u16* g, u16* l){
  __builtin_amdgcn_global_load_lds(
      (const __attribute__((address_space(1))) unsigned int*)(const void*)g,
      (__attribute__((address_space(3))) unsigned int*)(void*)l, 16, 0, 0);
}

// ---------------- K0: weight prep (SC folded into Wq path) ------------------
__global__ __launch_bounds__(256) void k_prep(
    const float* __restrict__ Wq, const float* __restrict__ W_in,
    const float* __restrict__ b_in, const float* __restrict__ bq,
    const float* __restrict__ Wk, const float* __restrict__ Wv,
    const float* __restrict__ Wout,
    u16* __restrict__ WqinBf, u16* __restrict__ WkBf, u16* __restrict__ WvBf,
    u16* __restrict__ WoutBf, float* __restrict__ bq_eff)
{
  int blk = blockIdx.x, t = threadIdx.x;
  const float SC = 0.0625f;   // EMB^-0.5, exact power of two
  if (blk < 256) {
    int e = blk, c = t;
    float s = 0.f;
    #pragma unroll 8
    for (int f = 0; f < 256; f++) s += Wq[e*256+f] * W_in[f*256+c];
    WqinBf[e*256+c] = f2bf(s * SC);
    __shared__ float rb[4];
    float pb = Wq[e*256+t] * b_in[t];
    pb += __shfl_xor(pb, 1);  pb += __shfl_xor(pb, 2);
    pb += __shfl_xor(pb, 4);  pb += __shfl_xor(pb, 8);
    pb += __shfl_xor(pb, 16); pb += __shfl_xor(pb, 32);
    if ((t & 63) == 0) rb[t >> 6] = pb;
    __syncthreads();
    if (t == 0) bq_eff[e] = (rb[0]+rb[1]+rb[2]+rb[3] + bq[e]) * SC;
  } else {
    u32 flat = (u32)(blk - 256) * 256 + t;
    for (u32 idx = flat; idx < 131072u; idx += 16384u) {
      if (idx < 32768u)       WkBf[idx]          = f2bf(Wk[idx]);
      else if (idx < 65536u)  WvBf[idx - 32768u] = f2bf(Wv[idx - 32768u]);
      else                    WoutBf[idx - 65536u] = f2bf(Wout[idx - 65536u]);
    }
  }
}

// ---------------- K1: Q projection (Q pre-scaled by SC) ---------------------
__global__ __launch_bounds__(256) void k_qproj(
    const float* __restrict__ x, const u16* __restrict__ WqinBf,
    const float* __restrict__ bq_eff, u16* __restrict__ Qbf)
{
  int b = blockIdx.y, ibase = blockIdx.x * 64;
  int t = threadIdx.x, wv = t >> 6, lane = t & 63, g4 = lane >> 4, r16 = lane & 15;
  int e0 = wv * 64;
  f32x4 acc[4][4] = {};
  #pragma unroll 2
  for (int kk = 0; kk < 8; kk++) {
    bf16x8 a[4];
    #pragma unroll
    for (int m = 0; m < 4; m++)
      a[m] = ld16(WqinBf + (size_t)(e0 + m*16 + r16) * 256 + kk*32 + g4*8);
    bf16x8 bb[4];
    #pragma unroll
    for (int n = 0; n < 4; n++) {
      const float* xp = x + ((size_t)b*CH + kk*32 + g4*8) * HW + ibase + n*16 + r16;
      bb[n] = mk8(xp[0], xp[HW], xp[2*HW], xp[3*HW], xp[4*HW], xp[5*HW], xp[6*HW], xp[7*HW]);
    }
    #pragma unroll
    for (int m = 0; m < 4; m++)
      #pragma unroll
      for (int n = 0; n < 4; n++)
        acc[m][n] = MFMA(a[m], bb[n], acc[m][n]);
  }
  #pragma unroll
  for (int m = 0; m < 4; m++) {
    int e = e0 + m*16 + g4*4;
    float b0 = bq_eff[e], b1 = bq_eff[e+1], b2 = bq_eff[e+2], b3 = bq_eff[e+3];
    #pragma unroll
    for (int n = 0; n < 4; n++) {
      int i = ibase + n*16 + r16;
      u32 lo = (u32)f2bf(acc[m][n][0] + b0) | ((u32)f2bf(acc[m][n][1] + b1) << 16);
      u32 hi = (u32)f2bf(acc[m][n][2] + b2) | ((u32)f2bf(acc[m][n][3] + b3) << 16);
      *(uint2*)(Qbf + ((size_t)b*HW + i) * EMB + e) = make_uint2(lo, hi);
    }
  }
}

// ---------------- K2: K & V projections -------------------------------------
__global__ __launch_bounds__(512) void k_kvproj(
    const float* __restrict__ ctx, const u16* __restrict__ WkBf, const u16* __restrict__ WvBf,
    const float* __restrict__ bk, const float* __restrict__ bv,
    u16* __restrict__ Kbf, u16* __restrict__ Vtb)
{
  int b = blockIdx.y, sbase = blockIdx.x * 64;
  int t = threadIdx.x, wv = t >> 6, lane = t & 63, g4 = lane >> 4, r16 = lane & 15;
  bool isV = wv >= 4;
  int e0 = (wv & 3) * 64;
  const u16* Wsel = isV ? WvBf : WkBf;
  f32x4 acc[4][4] = {};
  #pragma unroll
  for (int kk = 0; kk < 4; kk++) {
    bf16x8 a[4];
    #pragma unroll
    for (int m = 0; m < 4; m++)
      a[m] = ld16(Wsel + (size_t)(e0 + m*16 + r16) * 128 + kk*32 + g4*8);
    bf16x8 bb[4];
    #pragma unroll
    for (int n = 0; n < 4; n++) {
      const float* cp = ctx + ((size_t)b*SEQ + sbase + n*16 + r16) * CTXD + kk*32 + g4*8;
      float4 lo = *(const float4*)cp;
      float4 hi = *(const float4*)(cp + 4);
      bb[n] = mk8(lo.x, lo.y, lo.z, lo.w, hi.x, hi.y, hi.z, hi.w);
    }
    #pragma unroll
    for (int m = 0; m < 4; m++)
      #pragma unroll
      for (int n = 0; n < 4; n++)
        acc[m][n] = MFMA(a[m], bb[n], acc[m][n]);
  }
  if (!isV) {
    #pragma unroll
    for (int m = 0; m < 4; m++) {
      int e = e0 + m*16 + g4*4;
      float b0 = bk[e], b1 = bk[e+1], b2 = bk[e+2], b3 = bk[e+3];
      #pragma unroll
      for (int n = 0; n < 4; n++) {
        int s = sbase + n*16 + r16;
        u32 lo = (u32)f2bf(acc[m][n][0] + b0) | ((u32)f2bf(acc[m][n][1] + b1) << 16);
        u32 hi = (u32)f2bf(acc[m][n][2] + b2) | ((u32)f2bf(acc[m][n][3] + b3) << 16);
        *(uint2*)(Kbf + ((size_t)b*SEQ + s) * EMB + e) = make_uint2(lo, hi);
      }
    }
  } else {
    #pragma unroll
    for (int m = 0; m < 4; m++) {
      #pragma unroll
      for (int r = 0; r < 4; r++) {
        int e = e0 + m*16 + g4*4 + r;
        float bvv = bv[e];
        #pragma unroll
        for (int n = 0; n < 4; n++) {
          int s = sbase + n*16 + r16;
          Vtb[((size_t)b*EMB + e) * SEQ + s] = f2bf(acc[m][n][r] + bvv);
        }
      }
    }
  }
}

// ---------------- K3a: S=QK^T -> E=exp (GEMM 128x128, K=256, dbuf LDS) ------
// R14 + double-buffered staging (stage ks+1 before compute ks, 1 barrier/iter).
// LDS 66.5 KB -> still 2 blocks/CU (VGPR=112 already caps there).
__global__ __launch_bounds__(512, 4) void k_qk(
    const u16* __restrict__ Qbf, const u16* __restrict__ Kbf,
    const int* __restrict__ mask, float* __restrict__ dout,
    float* __restrict__ gpart)
{
  __shared__ u16 lsA[2][128*64];  // Q tiles, dbuf (col8 XOR row&7)
  __shared__ u16 lsB[2][128*64];  // K tiles, dbuf
  __shared__ float red[4][128];

  int bid = blockIdx.x;
  int work = (bid & 7) * 576 + (bid >> 3);
  int b = work / 288, rem = work % 288;
  int mt = rem / 16, jt = rem % 16;
  int mbase = mt * 128, jbase = jt * 128;
  size_t bH = (size_t)b * HW, bS = (size_t)b * SEQ;

  int t = threadIdx.x, lane = t & 63, wv = t >> 6, g4 = lane >> 4, r16 = lane & 15;
  int wr = wv >> 2, wc = wv & 3;       // wave tile: i in [wr*64,+64), j in [wc*32,+32)

  // mask: 32 independent scalars, issued up-front (unchanged from R14)
  int mreg[4][2][4];
  {
    const int* mp = mask + (bH + mbase + wr*64 + g4*4) * SEQ + jbase + wc*32 + r16;
    #pragma unroll
    for (int m = 0; m < 4; m++)
      #pragma unroll
      for (int n = 0; n < 2; n++)
        #pragma unroll
        for (int r = 0; r < 4; r++)
          mreg[m][n][r] = mp[(size_t)(m*16 + r) * SEQ + n*16];
  }

  // staging map (source pre-swizzled, LDS dest linear)
  int i0 = t, i1 = t + 512;
  int r0 = i0 >> 3, c0 = (i0 & 7) ^ (r0 & 7);
  int r1 = i1 >> 3, c1 = (i1 & 7) ^ (r1 & 7);
  const u16* qs0 = Qbf + (bH + mbase + r0) * 256 + c0*8;
  const u16* qs1 = Qbf + (bH + mbase + r1) * 256 + c1*8;
  const u16* ks0 = Kbf + (bS + jbase + r0) * 256 + c0*8;
  const u16* ks1 = Kbf + (bS + jbase + r1) * 256 + c1*8;

  f32x4 acc[4][2] = {};

  // prologue: stage ks=0 into buf 0
  gload16(qs0, lsA[0] + i0*8);
  gload16(qs1, lsA[0] + i1*8);
  gload16(ks0, lsB[0] + i0*8);
  gload16(ks1, lsB[0] + i1*8);
  __syncthreads();

  int cur = 0;
  #pragma unroll
  for (int ks = 0; ks < 4; ks++) {
    if (ks < 3) {                      // stage next tile FIRST (overlaps compute)
      int nb = cur ^ 1;
      gload16(qs0 + (ks+1)*64, lsA[nb] + i0*8);
      gload16(qs1 + (ks+1)*64, lsA[nb] + i1*8);
      gload16(ks0 + (ks+1)*64, lsB[nb] + i0*8);
      gload16(ks1 + (ks+1)*64, lsB[nb] + i1*8);
    }
    const char* lA = (const char*)lsA[cur];
    const char* lB = (const char*)lsB[cur];
    #pragma unroll
    for (int kk = 0; kk < 2; kk++) {
      bf16x8 af[4], bf[2];
      #pragma unroll
      for (int m = 0; m < 4; m++) {
        int row = wr*64 + m*16 + r16;
        af[m] = ld16c(lA + row*128 + (((kk<<2)|g4) ^ (row&7))*16);
      }
      #pragma unroll
      for (int n = 0; n < 2; n++) {
        int row = wc*32 + n*16 + r16;
        bf[n] = ld16c(lB + row*128 + (((kk<<2)|g4) ^ (row&7))*16);
      }
      #pragma unroll
      for (int m = 0; m < 4; m++)
        #pragma unroll
        for (int n = 0; n < 2; n++)
          acc[m][n] = MFMA(af[m], bf[n], acc[m][n]);
    }
    if (ks < 3) __syncthreads();       // one drain+barrier per iter
    cur ^= 1;
  }

  // epilogue: mask, exp, E store (bf16 upper half of att rows), rowsums
  u16* Ebase = (u16*)(dout + OUT0);
  float part[4][4] = {};
  #pragma unroll
  for (int m = 0; m < 4; m++)
    #pragma unroll
    for (int n = 0; n < 2; n++)
      #pragma unroll
      for (int r = 0; r < 4; r++) {
        float e = mreg[m][n][r] ? 0.f : __expf(acc[m][n][r]);
        part[m][r] += e;
        int i = wr*64 + m*16 + g4*4 + r;
        int j = jbase + wc*32 + n*16 + r16;
        Ebase[(bH + mbase + i) * 4096 + 2048 + j] = f2bf(e);
      }
  #pragma unroll
  for (int m = 0; m < 4; m++)
    #pragma unroll
    for (int r = 0; r < 4; r++) {
      float v = part[m][r];
      v += __shfl_xor(v, 1); v += __shfl_xor(v, 2);
      v += __shfl_xor(v, 4); v += __shfl_xor(v, 8);
      if (r16 == 0) red[wc][wr*64 + m*16 + g4*4 + r] = v;
    }
  __syncthreads();
  if (t < 128) {
    float tot = red[0][t] + red[1][t] + red[2][t] + red[3][t];
    gpart[(bH + mbase + t) * 16 + jt] = tot;
  }
}

// ---------------- K3c: O = (E V) * inv — pure m97-style GEMM ---------------
// 128x128 tile (M=rows, N=emb), BK=64, 256 thr / 4 waves, 32 KB LDS, 2-barrier.
__global__ __launch_bounds__(256, 3) void k_pv(
    const u16* __restrict__ Vtb, const float* __restrict__ gpart,
    const float* __restrict__ dout, u16* __restrict__ Obf)
{
  __shared__ u16 lsA[128*64];     // E tile  [128 i][64 k], swizzled
  __shared__ u16 lsB[128*64];     // Vt tile [128 e][64 k], swizzled
  __shared__ float invl[128];

  int bid = blockIdx.x;                 // 576 = 8 * 72
  int work = (bid & 7) * 72 + (bid >> 3);
  int b = work / 36, rem = work % 36;
  int mt = rem >> 1, nt = rem & 1;
  int mbase = mt * 128, ebase = nt * 128;
  size_t bH = (size_t)b * HW;

  int t = threadIdx.x, lane = t & 63, wv = t >> 6, g4 = lane >> 4, r16 = lane & 15;
  int wr = wv >> 1, wc = wv & 1;        // wave: rows [wr*64,+64), emb [wc*64,+64)

  // inline inv: sum gpart row (16 partials)
  if (t < 128) {
    const float4* pp = (const float4*)(gpart + (bH + mbase + t) * 16);
    float4 p0 = pp[0], p1 = pp[1], p2 = pp[2], p3 = pp[3];
    invl[t] = 1.f / (p0.x+p0.y+p0.z+p0.w + p1.x+p1.y+p1.z+p1.w
                   + p2.x+p2.y+p2.z+p2.w + p3.x+p3.y+p3.z+p3.w);
  }

  const u16* Ebase = (const u16*)(dout + OUT0);
  // staging: 1024 slots each, 4/thread (source pre-swizzled, dest linear)
  int rs[4], cs[4];
  #pragma unroll
  for (int q = 0; q < 4; q++) {
    int idx = q*256 + t;
    rs[q] = idx >> 3;
    cs[q] = (idx & 7) ^ (rs[q] & 7);
  }
  const char* lA = (const char*)lsA;
  const char* lB = (const char*)lsB;

  f32x4 acc[4][4] = {};
  #pragma unroll 1
  for (int ks = 0; ks < 32; ks++) {
    int kb = ks * 64;
    #pragma unroll
    for (int q = 0; q < 4; q++) {
      gload16(Ebase + (bH + mbase + rs[q]) * 4096 + 2048 + kb + cs[q]*8,
              lsA + (q*256 + t)*8);
      gload16(Vtb + ((size_t)b*EMB + ebase + rs[q]) * SEQ + kb + cs[q]*8,
              lsB + (q*256 + t)*8);
    }
    __syncthreads();
    #pragma unroll
    for (int kk = 0; kk < 2; kk++) {
      bf16x8 af[4], bf[4];
      #pragma unroll
      for (int m = 0; m < 4; m++) {
        int row = wr*64 + m*16 + r16;
        af[m] = ld16c(lA + row*128 + (((kk<<2)|g4) ^ (row&7))*16);
      }
      #pragma unroll
      for (int n = 0; n < 4; n++) {
        int row = wc*64 + n*16 + r16;
        bf[n] = ld16c(lB + row*128 + (((kk<<2)|g4) ^ (row&7))*16);
      }
      #pragma unroll
      for (int m = 0; m < 4; m++)
        #pragma unroll
        for (int n = 0; n < 4; n++)
          acc[m][n] = MFMA(af[m], bf[n], acc[m][n]);
    }
    __syncthreads();
  }

  // epilogue: normalize by invl, store O bf16
  #pragma unroll
  for (int m = 0; m < 4; m++)
    #pragma unroll
    for (int r = 0; r < 4; r++) {
      int i = wr*64 + m*16 + g4*4 + r;
      float iv = invl[i];
      #pragma unroll
      for (int n = 0; n < 4; n++) {
        int e = ebase + wc*64 + n*16 + r16;
        Obf[(bH + mbase + i) * 256 + e] = f2bf(acc[m][n][r] * iv);
      }
    }
}

// ---------------- K3d: att = E * inv — pure streaming (destroys E) ----------
__global__ __launch_bounds__(512, 4) void k_att(
    const float* __restrict__ gpart, float* __restrict__ dout)
{
  int bid = blockIdx.x;                 // 2304 = 8 * 288
  int work = (bid & 7) * 288 + (bid >> 3);
  int t = threadIdx.x, wv = t >> 6, lane = t & 63;

  #pragma unroll
  for (int rr = 0; rr < 2; rr++) {
    size_t row = (size_t)work * 16 + wv * 2 + rr;
    const u16* Erow = (const u16*)(dout + OUT0) + row * 4096 + 2048;
    float* arow = dout + OUT0 + row * 2048;
    // inline inv: 16-lane-group reduce over gpart partials (redundant x4, cheap)
    float v = gpart[row * 16 + (lane & 15)];
    v += __shfl_xor(v, 1); v += __shfl_xor(v, 2);
    v += __shfl_xor(v, 4); v += __shfl_xor(v, 8);
    float iv = 1.f / v;
    // read all 8 uint2 (E bf16) first
    uint2 raw[8];
    #pragma unroll
    for (int seg = 0; seg < 8; seg++)
      raw[seg] = *(const uint2*)(Erow + (size_t)(seg*64 + lane) * 4);
    asm volatile("s_waitcnt vmcnt(0)" ::: "memory");
    // then write all 8 float4 (att) — clobbers E region of this row only
    #pragma unroll
    for (int seg = 0; seg < 8; seg++) {
      float4 o;
      o.x = bf2f(raw[seg].x & 0xffffu) * iv;
      o.y = bf2f(raw[seg].x >> 16)     * iv;
      o.z = bf2f(raw[seg].y & 0xffffu) * iv;
      o.w = bf2f(raw[seg].y >> 16)     * iv;
      *(float4*)(arow + (size_t)(seg*64 + lane) * 4) = o;
    }
  }
}

// ---------------- K4: out projection ----------------------------------------
__global__ __launch_bounds__(256) void k_outproj(
    const u16* __restrict__ Obf, const u16* __restrict__ WoutBf,
    const float* __restrict__ bout, float* __restrict__ out)
{
  int b = blockIdx.y, ibase = blockIdx.x * 64;
  int t = threadIdx.x, wv = t >> 6, lane = t & 63, g4 = lane >> 4, r16 = lane & 15;
  int c0 = wv * 64;
  f32x4 acc[4][4] = {};
  #pragma unroll 2
  for (int kk = 0; kk < 8; kk++) {
    bf16x8 a[4];
    #pragma unroll
    for (int m = 0; m < 4; m++)
      a[m] = ld16(WoutBf + (size_t)(c0 + m*16 + r16) * 256 + kk*32 + g4*8);
    bf16x8 bb[4];
    #pragma unroll
    for (int n = 0; n < 4; n++)
      bb[n] = ld16(Obf + ((size_t)b*HW + ibase + n*16 + r16) * EMB + kk*32 + g4*8);
    #pragma unroll
    for (int m = 0; m < 4; m++)
      #pragma unroll
      for (int n = 0; n < 4; n++)
        acc[m][n] = MFMA(a[m], bb[n], acc[m][n]);
  }
  #pragma unroll
  for (int m = 0; m < 4; m++) {
    #pragma unroll
    for (int r = 0; r < 4; r++) {
      int c = c0 + m*16 + g4*4 + r;
      float bo = bout[c];
      #pragma unroll
      for (int n = 0; n < 4; n++) {
        int i = ibase + n*16 + r16;
        out[((size_t)b*CH + c) * HW + i] = acc[m][n][r] + bo;
      }
    }
  }
}

// ---------------- host ------------------------------------------------------
extern "C" void kernel_launch(void* const* d_in, const int* in_sizes, int n_in,
                              void* d_out, int out_size, void* d_ws, size_t ws_size,
                              hipStream_t stream)
{
  const float* x    = (const float*)d_in[0];
  const float* ctx  = (const float*)d_in[1];
  const int*   mask = (const int*)  d_in[2];
  const float* W_in = (const float*)d_in[3];
  const float* b_in = (const float*)d_in[4];
  const float* Wq   = (const float*)d_in[5];
  const float* bq   = (const float*)d_in[6];
  const float* Wk   = (const float*)d_in[7];
  const float* bk   = (const float*)d_in[8];
  const float* Wv   = (const float*)d_in[9];
  const float* bv   = (const float*)d_in[10];
  const float* Wout = (const float*)d_in[11];
  const float* bout = (const float*)d_in[12];
  float* out = (float*)d_out;

  char* ws = (char*)d_ws;
  size_t off = 0;
  auto alloc = [&](size_t bytes) -> void* {
    void* p = ws + off;
    off += (bytes + 255) & ~(size_t)255;
    return p;
  };
  u16*   WqinBf = (u16*)  alloc(256*256*2);
  u16*   WkBf   = (u16*)  alloc(256*128*2);
  u16*   WvBf   = (u16*)  alloc(256*128*2);
  u16*   WoutBf = (u16*)  alloc(256*256*2);
  float* bq_eff = (float*)alloc(256*4);
  float* gpart  = (float*)alloc((size_t)BB*HW*16*4);
  u16*   Qbf    = (u16*)  alloc((size_t)BB*HW*EMB*2);   // reused as O by k_pv
  u16*   Kbf    = (u16*)  alloc((size_t)BB*SEQ*EMB*2);
  u16*   Vtb    = (u16*)  alloc((size_t)BB*EMB*SEQ*2);
  if (off > ws_size) return;  // diagnostic bail

  k_prep<<<dim3(320), dim3(256), 0, stream>>>(Wq, W_in, b_in, bq, Wk, Wv, Wout,
                                              WqinBf, WkBf, WvBf, WoutBf, bq_eff);
  k_qproj<<<dim3(36, 16), dim3(256), 0, stream>>>(x, WqinBf, bq_eff, Qbf);
  k_kvproj<<<dim3(32, 16), dim3(512), 0, stream>>>(ctx, WkBf, WvBf, bk, bv, Kbf, Vtb);
  k_qk<<<dim3(4608), dim3(512), 0, stream>>>(Qbf, Kbf, mask, out, gpart);
  k_pv<<<dim3(576), dim3(256), 0, stream>>>(Vtb, gpart, out, Qbf /*O*/);   // BEFORE k_att!
  k_att<<<dim3(2304), dim3(512), 0, stream>>>(gpart, out);                 // destroys E
  k_outproj<<<dim3(36, 16), dim3(256), 0, stream>>>(Qbf /*O*/, WoutBf, bout, out);
}

// Round 16
// 408.271 us; speedup vs baseline: 1.0267x; 1.0267x over previous
//
#include <hip/hip_runtime.h>

typedef unsigned short u16;
typedef unsigned int   u32;
typedef __attribute__((ext_vector_type(8))) __bf16 bf16x8;
typedef __attribute__((ext_vector_type(4))) float  f32x4;

#define BB   16
#define CH   256
#define HW   2304
#define SEQ  2048
#define EMB  256
#define CTXD 128
#define OUT0 9437184   // 16*256*2304, float offset of att region in d_out

#define MFMA(a,b,c) __builtin_amdgcn_mfma_f32_16x16x32_bf16(a,b,c,0,0,0)

__device__ __forceinline__ u16 f2bf(float f){
  u32 u = __builtin_bit_cast(u32, f);
  u += 0x7fffu + ((u >> 16) & 1u);
  return (u16)(u >> 16);
}
__device__ __forceinline__ float bf2f(u32 us){ return __builtin_bit_cast(float, us << 16); }

__device__ __forceinline__ bf16x8 ld16(const u16* p){
  uint4 q = *reinterpret_cast<const uint4*>(p);
  return __builtin_bit_cast(bf16x8, q);
}
__device__ __forceinline__ bf16x8 ld16c(const char* p){
  uint4 q = *reinterpret_cast<const uint4*>(p);
  return __builtin_bit_cast(bf16x8, q);
}
__device__ __forceinline__ bf16x8 mk8(float a0,float a1,float a2,float a3,
                                      float a4,float a5,float a6,float a7){
  uint4 q;
  q.x = (u32)f2bf(a0) | ((u32)f2bf(a1) << 16);
  q.y = (u32)f2bf(a2) | ((u32)f2bf(a3) << 16);
  q.z = (u32)f2bf(a4) | ((u32)f2bf(a5) << 16);
  q.w = (u32)f2bf(a6) | ((u32)f2bf(a7) << 16);
  return __builtin_bit_cast(bf16x8, q);
}
// async global->LDS, 16B per lane (dest linear: base + lane*16)
__device__ __forceinline__ void gload16(const u16* g, u16* l){
  __builtin_amdgcn_global_load_lds(
      (const __attribute__((address_space(1))) unsigned int*)(const void*)g,
      (__attribute__((address_space(3))) unsigned int*)(void*)l, 16, 0, 0);
}

// ---------------- K0: weight prep (SC folded into Wq path) ------------------
__global__ __launch_bounds__(256) void k_prep(
    const float* __restrict__ Wq, const float* __restrict__ W_in,
    const float* __restrict__ b_in, const float* __restrict__ bq,
    const float* __restrict__ Wk, const float* __restrict__ Wv,
    const float* __restrict__ Wout,
    u16* __restrict__ WqinBf, u16* __restrict__ WkBf, u16* __restrict__ WvBf,
    u16* __restrict__ WoutBf, float* __restrict__ bq_eff)
{
  int blk = blockIdx.x, t = threadIdx.x;
  const float SC = 0.0625f;   // EMB^-0.5, exact power of two
  if (blk < 256) {
    int e = blk, c = t;
    float s = 0.f;
    #pragma unroll 8
    for (int f = 0; f < 256; f++) s += Wq[e*256+f] * W_in[f*256+c];
    WqinBf[e*256+c] = f2bf(s * SC);
    __shared__ float rb[4];
    float pb = Wq[e*256+t] * b_in[t];
    pb += __shfl_xor(pb, 1);  pb += __shfl_xor(pb, 2);
    pb += __shfl_xor(pb, 4);  pb += __shfl_xor(pb, 8);
    pb += __shfl_xor(pb, 16); pb += __shfl_xor(pb, 32);
    if ((t & 63) == 0) rb[t >> 6] = pb;
    __syncthreads();
    if (t == 0) bq_eff[e] = (rb[0]+rb[1]+rb[2]+rb[3] + bq[e]) * SC;
  } else {
    u32 flat = (u32)(blk - 256) * 256 + t;
    for (u32 idx = flat; idx < 131072u; idx += 16384u) {
      if (idx < 32768u)       WkBf[idx]          = f2bf(Wk[idx]);
      else if (idx < 65536u)  WvBf[idx - 32768u] = f2bf(Wv[idx - 32768u]);
      else                    WoutBf[idx - 65536u] = f2bf(Wout[idx - 65536u]);
    }
  }
}

// ---------------- K1: Q projection (Q pre-scaled by SC) ---------------------
__global__ __launch_bounds__(256) void k_qproj(
    const float* __restrict__ x, const u16* __restrict__ WqinBf,
    const float* __restrict__ bq_eff, u16* __restrict__ Qbf)
{
  int b = blockIdx.y, ibase = blockIdx.x * 64;
  int t = threadIdx.x, wv = t >> 6, lane = t & 63, g4 = lane >> 4, r16 = lane & 15;
  int e0 = wv * 64;
  f32x4 acc[4][4] = {};
  #pragma unroll 2
  for (int kk = 0; kk < 8; kk++) {
    bf16x8 a[4];
    #pragma unroll
    for (int m = 0; m < 4; m++)
      a[m] = ld16(WqinBf + (size_t)(e0 + m*16 + r16) * 256 + kk*32 + g4*8);
    bf16x8 bb[4];
    #pragma unroll
    for (int n = 0; n < 4; n++) {
      const float* xp = x + ((size_t)b*CH + kk*32 + g4*8) * HW + ibase + n*16 + r16;
      bb[n] = mk8(xp[0], xp[HW], xp[2*HW], xp[3*HW], xp[4*HW], xp[5*HW], xp[6*HW], xp[7*HW]);
    }
    #pragma unroll
    for (int m = 0; m < 4; m++)
      #pragma unroll
      for (int n = 0; n < 4; n++)
        acc[m][n] = MFMA(a[m], bb[n], acc[m][n]);
  }
  #pragma unroll
  for (int m = 0; m < 4; m++) {
    int e = e0 + m*16 + g4*4;
    float b0 = bq_eff[e], b1 = bq_eff[e+1], b2 = bq_eff[e+2], b3 = bq_eff[e+3];
    #pragma unroll
    for (int n = 0; n < 4; n++) {
      int i = ibase + n*16 + r16;
      u32 lo = (u32)f2bf(acc[m][n][0] + b0) | ((u32)f2bf(acc[m][n][1] + b1) << 16);
      u32 hi = (u32)f2bf(acc[m][n][2] + b2) | ((u32)f2bf(acc[m][n][3] + b3) << 16);
      *(uint2*)(Qbf + ((size_t)b*HW + i) * EMB + e) = make_uint2(lo, hi);
    }
  }
}

// ---------------- K2: K & V projections -------------------------------------
__global__ __launch_bounds__(512) void k_kvproj(
    const float* __restrict__ ctx, const u16* __restrict__ WkBf, const u16* __restrict__ WvBf,
    const float* __restrict__ bk, const float* __restrict__ bv,
    u16* __restrict__ Kbf, u16* __restrict__ Vtb)
{
  int b = blockIdx.y, sbase = blockIdx.x * 64;
  int t = threadIdx.x, wv = t >> 6, lane = t & 63, g4 = lane >> 4, r16 = lane & 15;
  bool isV = wv >= 4;
  int e0 = (wv & 3) * 64;
  const u16* Wsel = isV ? WvBf : WkBf;
  f32x4 acc[4][4] = {};
  #pragma unroll
  for (int kk = 0; kk < 4; kk++) {
    bf16x8 a[4];
    #pragma unroll
    for (int m = 0; m < 4; m++)
      a[m] = ld16(Wsel + (size_t)(e0 + m*16 + r16) * 128 + kk*32 + g4*8);
    bf16x8 bb[4];
    #pragma unroll
    for (int n = 0; n < 4; n++) {
      const float* cp = ctx + ((size_t)b*SEQ + sbase + n*16 + r16) * CTXD + kk*32 + g4*8;
      float4 lo = *(const float4*)cp;
      float4 hi = *(const float4*)(cp + 4);
      bb[n] = mk8(lo.x, lo.y, lo.z, lo.w, hi.x, hi.y, hi.z, hi.w);
    }
    #pragma unroll
    for (int m = 0; m < 4; m++)
      #pragma unroll
      for (int n = 0; n < 4; n++)
        acc[m][n] = MFMA(a[m], bb[n], acc[m][n]);
  }
  if (!isV) {
    #pragma unroll
    for (int m = 0; m < 4; m++) {
      int e = e0 + m*16 + g4*4;
      float b0 = bk[e], b1 = bk[e+1], b2 = bk[e+2], b3 = bk[e+3];
      #pragma unroll
      for (int n = 0; n < 4; n++) {
        int s = sbase + n*16 + r16;
        u32 lo = (u32)f2bf(acc[m][n][0] + b0) | ((u32)f2bf(acc[m][n][1] + b1) << 16);
        u32 hi = (u32)f2bf(acc[m][n][2] + b2) | ((u32)f2bf(acc[m][n][3] + b3) << 16);
        *(uint2*)(Kbf + ((size_t)b*SEQ + s) * EMB + e) = make_uint2(lo, hi);
      }
    }
  } else {
    #pragma unroll
    for (int m = 0; m < 4; m++) {
      #pragma unroll
      for (int r = 0; r < 4; r++) {
        int e = e0 + m*16 + g4*4 + r;
        float bvv = bv[e];
        #pragma unroll
        for (int n = 0; n < 4; n++) {
          int s = sbase + n*16 + r16;
          Vtb[((size_t)b*EMB + e) * SEQ + s] = f2bf(acc[m][n][r] + bvv);
        }
      }
    }
  }
}

// ---------------- K3a: S=QK^T -> E=exp (GEMM 128x128, K=256, swizzled LDS) --
// (exact R10/R14 config — 405 us best run)
__global__ __launch_bounds__(512, 4) void k_qk(
    const u16* __restrict__ Qbf, const u16* __restrict__ Kbf,
    const int* __restrict__ mask, float* __restrict__ dout,
    float* __restrict__ gpart)
{
  __shared__ u16 lsA[128*64];     // Q tile  [128 i][64 k], col8 XOR row&7
  __shared__ u16 lsB[128*64];     // K tile  [128 j][64 k]
  __shared__ float red[4][128];

  int bid = blockIdx.x;
  int work = (bid & 7) * 576 + (bid >> 3);
  int b = work / 288, rem = work % 288;
  int mt = rem / 16, jt = rem % 16;
  int mbase = mt * 128, jbase = jt * 128;
  size_t bH = (size_t)b * HW, bS = (size_t)b * SEQ;

  int t = threadIdx.x, lane = t & 63, wv = t >> 6, g4 = lane >> 4, r16 = lane & 15;
  int wr = wv >> 2, wc = wv & 3;       // wave tile: i in [wr*64,+64), j in [wc*32,+32)

  // mask: 32 independent scalars, issued up-front
  int mreg[4][2][4];
  {
    const int* mp = mask + (bH + mbase + wr*64 + g4*4) * SEQ + jbase + wc*32 + r16;
    #pragma unroll
    for (int m = 0; m < 4; m++)
      #pragma unroll
      for (int n = 0; n < 2; n++)
        #pragma unroll
        for (int r = 0; r < 4; r++)
          mreg[m][n][r] = mp[(size_t)(m*16 + r) * SEQ + n*16];
  }

  // staging map (source pre-swizzled, LDS dest linear)
  int i0 = t, i1 = t + 512;
  int r0 = i0 >> 3, c0 = (i0 & 7) ^ (r0 & 7);
  int r1 = i1 >> 3, c1 = (i1 & 7) ^ (r1 & 7);
  const u16* qs0 = Qbf + (bH + mbase + r0) * 256 + c0*8;
  const u16* qs1 = Qbf + (bH + mbase + r1) * 256 + c1*8;
  const u16* ks0 = Kbf + (bS + jbase + r0) * 256 + c0*8;
  const u16* ks1 = Kbf + (bS + jbase + r1) * 256 + c1*8;
  u16 *dA0 = lsA + i0*8, *dA1 = lsA + i1*8, *dB0 = lsB + i0*8, *dB1 = lsB + i1*8;

  const char* lA = (const char*)lsA;
  const char* lB = (const char*)lsB;

  f32x4 acc[4][2] = {};
  #pragma unroll 1
  for (int ks = 0; ks < 4; ks++) {
    gload16(qs0 + ks*64, dA0);
    gload16(qs1 + ks*64, dA1);
    gload16(ks0 + ks*64, dB0);
    gload16(ks1 + ks*64, dB1);
    __syncthreads();
    #pragma unroll
    for (int kk = 0; kk < 2; kk++) {
      bf16x8 af[4], bf[2];
      #pragma unroll
      for (int m = 0; m < 4; m++) {
        int row = wr*64 + m*16 + r16;
        af[m] = ld16c(lA + row*128 + (((kk<<2)|g4) ^ (row&7))*16);
      }
      #pragma unroll
      for (int n = 0; n < 2; n++) {
        int row = wc*32 + n*16 + r16;
        bf[n] = ld16c(lB + row*128 + (((kk<<2)|g4) ^ (row&7))*16);
      }
      #pragma unroll
      for (int m = 0; m < 4; m++)
        #pragma unroll
        for (int n = 0; n < 2; n++)
          acc[m][n] = MFMA(af[m], bf[n], acc[m][n]);
    }
    __syncthreads();
  }

  // epilogue: mask, exp, E store (bf16 upper half of att rows), rowsums
  u16* Ebase = (u16*)(dout + OUT0);
  float part[4][4] = {};
  #pragma unroll
  for (int m = 0; m < 4; m++)
    #pragma unroll
    for (int n = 0; n < 2; n++)
      #pragma unroll
      for (int r = 0; r < 4; r++) {
        float e = mreg[m][n][r] ? 0.f : __expf(acc[m][n][r]);
        part[m][r] += e;
        int i = wr*64 + m*16 + g4*4 + r;
        int j = jbase + wc*32 + n*16 + r16;
        Ebase[(bH + mbase + i) * 4096 + 2048 + j] = f2bf(e);
      }
  #pragma unroll
  for (int m = 0; m < 4; m++)
    #pragma unroll
    for (int r = 0; r < 4; r++) {
      float v = part[m][r];
      v += __shfl_xor(v, 1); v += __shfl_xor(v, 2);
      v += __shfl_xor(v, 4); v += __shfl_xor(v, 8);
      if (r16 == 0) red[wc][wr*64 + m*16 + g4*4 + r] = v;
    }
  __syncthreads();
  if (t < 128) {
    float tot = red[0][t] + red[1][t] + red[2][t] + red[3][t];
    gpart[(bH + mbase + t) * 16 + jt] = tot;
  }
}

// ---------------- K3c: O = (E V) * inv — pure m97-style GEMM ---------------
// 128x128 tile (M=rows, N=emb), BK=64, 256 thr / 4 waves, 32 KB LDS, 2-barrier.
__global__ __launch_bounds__(256, 3) void k_pv(
    const u16* __restrict__ Vtb, const float* __restrict__ gpart,
    const float* __restrict__ dout, u16* __restrict__ Obf)
{
  __shared__ u16 lsA[128*64];     // E tile  [128 i][64 k], swizzled
  __shared__ u16 lsB[128*64];     // Vt tile [128 e][64 k], swizzled
  __shared__ float invl[128];

  int bid = blockIdx.x;                 // 576 = 8 * 72
  int work = (bid & 7) * 72 + (bid >> 3);
  int b = work / 36, rem = work % 36;
  int mt = rem >> 1, nt = rem & 1;
  int mbase = mt * 128, ebase = nt * 128;
  size_t bH = (size_t)b * HW;

  int t = threadIdx.x, lane = t & 63, wv = t >> 6, g4 = lane >> 4, r16 = lane & 15;
  int wr = wv >> 1, wc = wv & 1;        // wave: rows [wr*64,+64), emb [wc*64,+64)

  // inline inv: sum gpart row (16 partials)
  if (t < 128) {
    const float4* pp = (const float4*)(gpart + (bH + mbase + t) * 16);
    float4 p0 = pp[0], p1 = pp[1], p2 = pp[2], p3 = pp[3];
    invl[t] = 1.f / (p0.x+p0.y+p0.z+p0.w + p1.x+p1.y+p1.z+p1.w
                   + p2.x+p2.y+p2.z+p2.w + p3.x+p3.y+p3.z+p3.w);
  }

  const u16* Ebase = (const u16*)(dout + OUT0);
  // staging: 1024 slots each, 4/thread (source pre-swizzled, dest linear)
  int rs[4], cs[4];
  #pragma unroll
  for (int q = 0; q < 4; q++) {
    int idx = q*256 + t;
    rs[q] = idx >> 3;
    cs[q] = (idx & 7) ^ (rs[q] & 7);
  }
  const char* lA = (const char*)lsA;
  const char* lB = (const char*)lsB;

  f32x4 acc[4][4] = {};
  #pragma unroll 1
  for (int ks = 0; ks < 32; ks++) {
    int kb = ks * 64;
    #pragma unroll
    for (int q = 0; q < 4; q++) {
      gload16(Ebase + (bH + mbase + rs[q]) * 4096 + 2048 + kb + cs[q]*8,
              lsA + (q*256 + t)*8);
      gload16(Vtb + ((size_t)b*EMB + ebase + rs[q]) * SEQ + kb + cs[q]*8,
              lsB + (q*256 + t)*8);
    }
    __syncthreads();
    #pragma unroll
    for (int kk = 0; kk < 2; kk++) {
      bf16x8 af[4], bf[4];
      #pragma unroll
      for (int m = 0; m < 4; m++) {
        int row = wr*64 + m*16 + r16;
        af[m] = ld16c(lA + row*128 + (((kk<<2)|g4) ^ (row&7))*16);
      }
      #pragma unroll
      for (int n = 0; n < 4; n++) {
        int row = wc*64 + n*16 + r16;
        bf[n] = ld16c(lB + row*128 + (((kk<<2)|g4) ^ (row&7))*16);
      }
      #pragma unroll
      for (int m = 0; m < 4; m++)
        #pragma unroll
        for (int n = 0; n < 4; n++)
          acc[m][n] = MFMA(af[m], bf[n], acc[m][n]);
    }
    __syncthreads();
  }

  // epilogue: normalize by invl, store O bf16
  #pragma unroll
  for (int m = 0; m < 4; m++)
    #pragma unroll
    for (int r = 0; r < 4; r++) {
      int i = wr*64 + m*16 + g4*4 + r;
      float iv = invl[i];
      #pragma unroll
      for (int n = 0; n < 4; n++) {
        int e = ebase + wc*64 + n*16 + r16;
        Obf[(bH + mbase + i) * 256 + e] = f2bf(acc[m][n][r] * iv);
      }
    }
}

// ---------------- K3d: att = E * inv — pure streaming (destroys E) ----------
__global__ __launch_bounds__(512, 4) void k_att(
    const float* __restrict__ gpart, float* __restrict__ dout)
{
  int bid = blockIdx.x;                 // 2304 = 8 * 288
  int work = (bid & 7) * 288 + (bid >> 3);
  int t = threadIdx.x, wv = t >> 6, lane = t & 63;

  #pragma unroll
  for (int rr = 0; rr < 2; rr++) {
    size_t row = (size_t)work * 16 + wv * 2 + rr;
    const u16* Erow = (const u16*)(dout + OUT0) + row * 4096 + 2048;
    float* arow = dout + OUT0 + row * 2048;
    // inline inv: 16-lane-group reduce over gpart partials (redundant x4, cheap)
    float v = gpart[row * 16 + (lane & 15)];
    v += __shfl_xor(v, 1); v += __shfl_xor(v, 2);
    v += __shfl_xor(v, 4); v += __shfl_xor(v, 8);
    float iv = 1.f / v;
    // read all 8 uint2 (E bf16) first
    uint2 raw[8];
    #pragma unroll
    for (int seg = 0; seg < 8; seg++)
      raw[seg] = *(const uint2*)(Erow + (size_t)(seg*64 + lane) * 4);
    asm volatile("s_waitcnt vmcnt(0)" ::: "memory");
    // then write all 8 float4 (att) — clobbers E region of this row only
    #pragma unroll
    for (int seg = 0; seg < 8; seg++) {
      float4 o;
      o.x = bf2f(raw[seg].x & 0xffffu) * iv;
      o.y = bf2f(raw[seg].x >> 16)     * iv;
      o.z = bf2f(raw[seg].y & 0xffffu) * iv;
      o.w = bf2f(raw[seg].y >> 16)     * iv;
      *(float4*)(arow + (size_t)(seg*64 + lane) * 4) = o;
    }
  }
}

// ---------------- K4: out projection ----------------------------------------
__global__ __launch_bounds__(256) void k_outproj(
    const u16* __restrict__ Obf, const u16* __restrict__ WoutBf,
    const float* __restrict__ bout, float* __restrict__ out)
{
  int b = blockIdx.y, ibase = blockIdx.x * 64;
  int t = threadIdx.x, wv = t >> 6, lane = t & 63, g4 = lane >> 4, r16 = lane & 15;
  int c0 = wv * 64;
  f32x4 acc[4][4] = {};
  #pragma unroll 2
  for (int kk = 0; kk < 8; kk++) {
    bf16x8 a[4];
    #pragma unroll
    for (int m = 0; m < 4; m++)
      a[m] = ld16(WoutBf + (size_t)(c0 + m*16 + r16) * 256 + kk*32 + g4*8);
    bf16x8 bb[4];
    #pragma unroll
    for (int n = 0; n < 4; n++)
      bb[n] = ld16(Obf + ((size_t)b*HW + ibase + n*16 + r16) * EMB + kk*32 + g4*8);
    #pragma unroll
    for (int m = 0; m < 4; m++)
      #pragma unroll
      for (int n = 0; n < 4; n++)
        acc[m][n] = MFMA(a[m], bb[n], acc[m][n]);
  }
  #pragma unroll
  for (int m = 0; m < 4; m++) {
    #pragma unroll
    for (int r = 0; r < 4; r++) {
      int c = c0 + m*16 + g4*4 + r;
      float bo = bout[c];
      #pragma unroll
      for (int n = 0; n < 4; n++) {
        int i = ibase + n*16 + r16;
        out[((size_t)b*CH + c) * HW + i] = acc[m][n][r] + bo;
      }
    }
  }
}

// ---------------- host ------------------------------------------------------
extern "C" void kernel_launch(void* const* d_in, const int* in_sizes, int n_in,
                              void* d_out, int out_size, void* d_ws, size_t ws_size,
                              hipStream_t stream)
{
  const float* x    = (const float*)d_in[0];
  const float* ctx  = (const float*)d_in[1];
  const int*   mask = (const int*)  d_in[2];
  const float* W_in = (const float*)d_in[3];
  const float* b_in = (const float*)d_in[4];
  const float* Wq   = (const float*)d_in[5];
  const float* bq   = (const float*)d_in[6];
  const float* Wk   = (const float*)d_in[7];
  const float* bk   = (const float*)d_in[8];
  const float* Wv   = (const float*)d_in[9];
  const float* bv   = (const float*)d_in[10];
  const float* Wout = (const float*)d_in[11];
  const float* bout = (const float*)d_in[12];
  float* out = (float*)d_out;

  char* ws = (char*)d_ws;
  size_t off = 0;
  auto alloc = [&](size_t bytes) -> void* {
    void* p = ws + off;
    off += (bytes + 255) & ~(size_t)255;
    return p;
  };
  u16*   WqinBf = (u16*)  alloc(256*256*2);
  u16*   WkBf   = (u16*)  alloc(256*128*2);
  u16*   WvBf   = (u16*)  alloc(256*128*2);
  u16*   WoutBf = (u16*)  alloc(256*256*2);
  float* bq_eff = (float*)alloc(256*4);
  float* gpart  = (float*)alloc((size_t)BB*HW*16*4);
  u16*   Qbf    = (u16*)  alloc((size_t)BB*HW*EMB*2);   // reused as O by k_pv
  u16*   Kbf    = (u16*)  alloc((size_t)BB*SEQ*EMB*2);
  u16*   Vtb    = (u16*)  alloc((size_t)BB*EMB*SEQ*2);
  if (off > ws_size) return;  // diagnostic bail

  k_prep<<<dim3(320), dim3(256), 0, stream>>>(Wq, W_in, b_in, bq, Wk, Wv, Wout,
                                              WqinBf, WkBf, WvBf, WoutBf, bq_eff);
  k_qproj<<<dim3(36, 16), dim3(256), 0, stream>>>(x, WqinBf, bq_eff, Qbf);
  k_kvproj<<<dim3(32, 16), dim3(512), 0, stream>>>(ctx, WkBf, WvBf, bk, bv, Kbf, Vtb);
  k_qk<<<dim3(4608), dim3(512), 0, stream>>>(Qbf, Kbf, mask, out, gpart);
  k_pv<<<dim3(576), dim3(256), 0, stream>>>(Vtb, gpart, out, Qbf /*O*/);   // BEFORE k_att!
  k_att<<<dim3(2304), dim3(512), 0, stream>>>(gpart, out);                 // destroys E
  k_outproj<<<dim3(36, 16), dim3(256), 0, stream>>>(Qbf /*O*/, WoutBf, bout, out);
}

// Round 17
// 404.331 us; speedup vs baseline: 1.0367x; 1.0097x over previous
//
#include <hip/hip_runtime.h>

typedef unsigned short u16;
typedef unsigned int   u32;
typedef __attribute__((ext_vector_type(8))) __bf16 bf16x8;
typedef __attribute__((ext_vector_type(4))) float  f32x4;

#define BB   16
#define CH   256
#define HW   2304
#define SEQ  2048
#define EMB  256
#define CTXD 128
#define OUT0 9437184   // 16*256*2304, float offset of att region in d_out

#define MFMA(a,b,c) __builtin_amdgcn_mfma_f32_16x16x32_bf16(a,b,c,0,0,0)

__device__ __forceinline__ u16 f2bf(float f){
  u32 u = __builtin_bit_cast(u32, f);
  u += 0x7fffu + ((u >> 16) & 1u);
  return (u16)(u >> 16);
}
__device__ __forceinline__ float bf2f(u32 us){ return __builtin_bit_cast(float, us << 16); }

__device__ __forceinline__ bf16x8 ld16(const u16* p){
  uint4 q = *reinterpret_cast<const uint4*>(p);
  return __builtin_bit_cast(bf16x8, q);
}
__device__ __forceinline__ bf16x8 ld16c(const char* p){
  uint4 q = *reinterpret_cast<const uint4*>(p);
  return __builtin_bit_cast(bf16x8, q);
}
__device__ __forceinline__ bf16x8 mk8(float a0,float a1,float a2,float a3,
                                      float a4,float a5,float a6,float a7){
  uint4 q;
  q.x = (u32)f2bf(a0) | ((u32)f2bf(a1) << 16);
  q.y = (u32)f2bf(a2) | ((u32)f2bf(a3) << 16);
  q.z = (u32)f2bf(a4) | ((u32)f2bf(a5) << 16);
  q.w = (u32)f2bf(a6) | ((u32)f2bf(a7) << 16);
  return __builtin_bit_cast(bf16x8, q);
}
// async global->LDS, 16B per lane (dest linear: base + lane*16)
__device__ __forceinline__ void gload16(const u16* g, u16* l){
  __builtin_amdgcn_global_load_lds(
      (const __attribute__((address_space(1))) unsigned int*)(const void*)g,
      (__attribute__((address_space(3))) unsigned int*)(void*)l, 16, 0, 0);
}

// ---------------- K0: weight prep (SC folded into Wq path) ------------------
__global__ __launch_bounds__(256) void k_prep(
    const float* __restrict__ Wq, const float* __restrict__ W_in,
    const float* __restrict__ b_in, const float* __restrict__ bq,
    const float* __restrict__ Wk, const float* __restrict__ Wv,
    const float* __restrict__ Wout,
    u16* __restrict__ WqinBf, u16* __restrict__ WkBf, u16* __restrict__ WvBf,
    u16* __restrict__ WoutBf, float* __restrict__ bq_eff)
{
  int blk = blockIdx.x, t = threadIdx.x;
  const float SC = 0.0625f;   // EMB^-0.5, exact power of two
  if (blk < 256) {
    int e = blk, c = t;
    float s = 0.f;
    #pragma unroll 8
    for (int f = 0; f < 256; f++) s += Wq[e*256+f] * W_in[f*256+c];
    WqinBf[e*256+c] = f2bf(s * SC);
    __shared__ float rb[4];
    float pb = Wq[e*256+t] * b_in[t];
    pb += __shfl_xor(pb, 1);  pb += __shfl_xor(pb, 2);
    pb += __shfl_xor(pb, 4);  pb += __shfl_xor(pb, 8);
    pb += __shfl_xor(pb, 16); pb += __shfl_xor(pb, 32);
    if ((t & 63) == 0) rb[t >> 6] = pb;
    __syncthreads();
    if (t == 0) bq_eff[e] = (rb[0]+rb[1]+rb[2]+rb[3] + bq[e]) * SC;
  } else {
    u32 flat = (u32)(blk - 256) * 256 + t;
    for (u32 idx = flat; idx < 131072u; idx += 16384u) {
      if (idx < 32768u)       WkBf[idx]          = f2bf(Wk[idx]);
      else if (idx < 65536u)  WvBf[idx - 32768u] = f2bf(Wv[idx - 32768u]);
      else                    WoutBf[idx - 65536u] = f2bf(Wout[idx - 65536u]);
    }
  }
}

// ---------------- K1: merged Q + K/V projections (one dispatch) -------------
// blocks [0,576): Q-proj (256 active threads); blocks [576,1088): K/V-proj.
__global__ __launch_bounds__(512) void k_proj(
    const float* __restrict__ x, const u16* __restrict__ WqinBf,
    const float* __restrict__ bq_eff, u16* __restrict__ Qbf,
    const float* __restrict__ ctx, const u16* __restrict__ WkBf,
    const u16* __restrict__ WvBf, const float* __restrict__ bk,
    const float* __restrict__ bv, u16* __restrict__ Kbf, u16* __restrict__ Vtb)
{
  int bid = blockIdx.x;
  if (bid < 576) {
    // ---- Q projection (R14 k_qproj body, t<256) ----
    if (threadIdx.x >= 256) return;
    int b = bid / 36, ibase = (bid % 36) * 64;
    int t = threadIdx.x, wv = t >> 6, lane = t & 63, g4 = lane >> 4, r16 = lane & 15;
    int e0 = wv * 64;
    f32x4 acc[4][4] = {};
    #pragma unroll 2
    for (int kk = 0; kk < 8; kk++) {
      bf16x8 a[4];
      #pragma unroll
      for (int m = 0; m < 4; m++)
        a[m] = ld16(WqinBf + (size_t)(e0 + m*16 + r16) * 256 + kk*32 + g4*8);
      bf16x8 bb[4];
      #pragma unroll
      for (int n = 0; n < 4; n++) {
        const float* xp = x + ((size_t)b*CH + kk*32 + g4*8) * HW + ibase + n*16 + r16;
        bb[n] = mk8(xp[0], xp[HW], xp[2*HW], xp[3*HW], xp[4*HW], xp[5*HW], xp[6*HW], xp[7*HW]);
      }
      #pragma unroll
      for (int m = 0; m < 4; m++)
        #pragma unroll
        for (int n = 0; n < 4; n++)
          acc[m][n] = MFMA(a[m], bb[n], acc[m][n]);
    }
    #pragma unroll
    for (int m = 0; m < 4; m++) {
      int e = e0 + m*16 + g4*4;
      float b0 = bq_eff[e], b1 = bq_eff[e+1], b2 = bq_eff[e+2], b3 = bq_eff[e+3];
      #pragma unroll
      for (int n = 0; n < 4; n++) {
        int i = ibase + n*16 + r16;
        u32 lo = (u32)f2bf(acc[m][n][0] + b0) | ((u32)f2bf(acc[m][n][1] + b1) << 16);
        u32 hi = (u32)f2bf(acc[m][n][2] + b2) | ((u32)f2bf(acc[m][n][3] + b3) << 16);
        *(uint2*)(Qbf + ((size_t)b*HW + i) * EMB + e) = make_uint2(lo, hi);
      }
    }
  } else {
    // ---- K & V projections (R14 k_kvproj body) ----
    int b2 = bid - 576;
    int b = b2 / 32, sbase = (b2 % 32) * 64;
    int t = threadIdx.x, wv = t >> 6, lane = t & 63, g4 = lane >> 4, r16 = lane & 15;
    bool isV = wv >= 4;
    int e0 = (wv & 3) * 64;
    const u16* Wsel = isV ? WvBf : WkBf;
    f32x4 acc[4][4] = {};
    #pragma unroll
    for (int kk = 0; kk < 4; kk++) {
      bf16x8 a[4];
      #pragma unroll
      for (int m = 0; m < 4; m++)
        a[m] = ld16(Wsel + (size_t)(e0 + m*16 + r16) * 128 + kk*32 + g4*8);
      bf16x8 bb[4];
      #pragma unroll
      for (int n = 0; n < 4; n++) {
        const float* cp = ctx + ((size_t)b*SEQ + sbase + n*16 + r16) * CTXD + kk*32 + g4*8;
        float4 lo = *(const float4*)cp;
        float4 hi = *(const float4*)(cp + 4);
        bb[n] = mk8(lo.x, lo.y, lo.z, lo.w, hi.x, hi.y, hi.z, hi.w);
      }
      #pragma unroll
      for (int m = 0; m < 4; m++)
        #pragma unroll
        for (int n = 0; n < 4; n++)
          acc[m][n] = MFMA(a[m], bb[n], acc[m][n]);
    }
    if (!isV) {
      #pragma unroll
      for (int m = 0; m < 4; m++) {
        int e = e0 + m*16 + g4*4;
        float b0 = bk[e], b1 = bk[e+1], b2 = bk[e+2], b3 = bk[e+3];
        #pragma unroll
        for (int n = 0; n < 4; n++) {
          int s = sbase + n*16 + r16;
          u32 lo = (u32)f2bf(acc[m][n][0] + b0) | ((u32)f2bf(acc[m][n][1] + b1) << 16);
          u32 hi = (u32)f2bf(acc[m][n][2] + b2) | ((u32)f2bf(acc[m][n][3] + b3) << 16);
          *(uint2*)(Kbf + ((size_t)b*SEQ + s) * EMB + e) = make_uint2(lo, hi);
        }
      }
    } else {
      #pragma unroll
      for (int m = 0; m < 4; m++) {
        #pragma unroll
        for (int r = 0; r < 4; r++) {
          int e = e0 + m*16 + g4*4 + r;
          float bvv = bv[e];
          #pragma unroll
          for (int n = 0; n < 4; n++) {
            int s = sbase + n*16 + r16;
            Vtb[((size_t)b*EMB + e) * SEQ + s] = f2bf(acc[m][n][r] + bvv);
          }
        }
      }
    }
  }
}

// ---------------- K3a: S=QK^T -> E=exp (GEMM 128x128, K=256, swizzled LDS) --
// (exact R10/R14 config — 405 us best run)
__global__ __launch_bounds__(512, 4) void k_qk(
    const u16* __restrict__ Qbf, const u16* __restrict__ Kbf,
    const int* __restrict__ mask, float* __restrict__ dout,
    float* __restrict__ gpart)
{
  __shared__ u16 lsA[128*64];     // Q tile  [128 i][64 k], col8 XOR row&7
  __shared__ u16 lsB[128*64];     // K tile  [128 j][64 k]
  __shared__ float red[4][128];

  int bid = blockIdx.x;
  int work = (bid & 7) * 576 + (bid >> 3);
  int b = work / 288, rem = work % 288;
  int mt = rem / 16, jt = rem % 16;
  int mbase = mt * 128, jbase = jt * 128;
  size_t bH = (size_t)b * HW, bS = (size_t)b * SEQ;

  int t = threadIdx.x, lane = t & 63, wv = t >> 6, g4 = lane >> 4, r16 = lane & 15;
  int wr = wv >> 2, wc = wv & 3;       // wave tile: i in [wr*64,+64), j in [wc*32,+32)

  // mask: 32 independent scalars, issued up-front
  int mreg[4][2][4];
  {
    const int* mp = mask + (bH + mbase + wr*64 + g4*4) * SEQ + jbase + wc*32 + r16;
    #pragma unroll
    for (int m = 0; m < 4; m++)
      #pragma unroll
      for (int n = 0; n < 2; n++)
        #pragma unroll
        for (int r = 0; r < 4; r++)
          mreg[m][n][r] = mp[(size_t)(m*16 + r) * SEQ + n*16];
  }

  // staging map (source pre-swizzled, LDS dest linear)
  int i0 = t, i1 = t + 512;
  int r0 = i0 >> 3, c0 = (i0 & 7) ^ (r0 & 7);
  int r1 = i1 >> 3, c1 = (i1 & 7) ^ (r1 & 7);
  const u16* qs0 = Qbf + (bH + mbase + r0) * 256 + c0*8;
  const u16* qs1 = Qbf + (bH + mbase + r1) * 256 + c1*8;
  const u16* ks0 = Kbf + (bS + jbase + r0) * 256 + c0*8;
  const u16* ks1 = Kbf + (bS + jbase + r1) * 256 + c1*8;
  u16 *dA0 = lsA + i0*8, *dA1 = lsA + i1*8, *dB0 = lsB + i0*8, *dB1 = lsB + i1*8;

  const char* lA = (const char*)lsA;
  const char* lB = (const char*)lsB;

  f32x4 acc[4][2] = {};
  #pragma unroll 1
  for (int ks = 0; ks < 4; ks++) {
    gload16(qs0 + ks*64, dA0);
    gload16(qs1 + ks*64, dA1);
    gload16(ks0 + ks*64, dB0);
    gload16(ks1 + ks*64, dB1);
    __syncthreads();
    #pragma unroll
    for (int kk = 0; kk < 2; kk++) {
      bf16x8 af[4], bf[2];
      #pragma unroll
      for (int m = 0; m < 4; m++) {
        int row = wr*64 + m*16 + r16;
        af[m] = ld16c(lA + row*128 + (((kk<<2)|g4) ^ (row&7))*16);
      }
      #pragma unroll
      for (int n = 0; n < 2; n++) {
        int row = wc*32 + n*16 + r16;
        bf[n] = ld16c(lB + row*128 + (((kk<<2)|g4) ^ (row&7))*16);
      }
      #pragma unroll
      for (int m = 0; m < 4; m++)
        #pragma unroll
        for (int n = 0; n < 2; n++)
          acc[m][n] = MFMA(af[m], bf[n], acc[m][n]);
    }
    __syncthreads();
  }

  // epilogue: mask, exp, E store (bf16 upper half of att rows), rowsums
  u16* Ebase = (u16*)(dout + OUT0);
  float part[4][4] = {};
  #pragma unroll
  for (int m = 0; m < 4; m++)
    #pragma unroll
    for (int n = 0; n < 2; n++)
      #pragma unroll
      for (int r = 0; r < 4; r++) {
        float e = mreg[m][n][r] ? 0.f : __expf(acc[m][n][r]);
        part[m][r] += e;
        int i = wr*64 + m*16 + g4*4 + r;
        int j = jbase + wc*32 + n*16 + r16;
        Ebase[(bH + mbase + i) * 4096 + 2048 + j] = f2bf(e);
      }
  #pragma unroll
  for (int m = 0; m < 4; m++)
    #pragma unroll
    for (int r = 0; r < 4; r++) {
      float v = part[m][r];
      v += __shfl_xor(v, 1); v += __shfl_xor(v, 2);
      v += __shfl_xor(v, 4); v += __shfl_xor(v, 8);
      if (r16 == 0) red[wc][wr*64 + m*16 + g4*4 + r] = v;
    }
  __syncthreads();
  if (t < 128) {
    float tot = red[0][t] + red[1][t] + red[2][t] + red[3][t];
    gpart[(bH + mbase + t) * 16 + jt] = tot;
  }
}

// ---------------- K3c: O = (E V) * inv — pure m97-style GEMM ---------------
// 128x128 tile (M=rows, N=emb), BK=64, 256 thr / 4 waves, 32 KB LDS, 2-barrier.
__global__ __launch_bounds__(256, 3) void k_pv(
    const u16* __restrict__ Vtb, const float* __restrict__ gpart,
    const float* __restrict__ dout, u16* __restrict__ Obf)
{
  __shared__ u16 lsA[128*64];     // E tile  [128 i][64 k], swizzled
  __shared__ u16 lsB[128*64];     // Vt tile [128 e][64 k], swizzled
  __shared__ float invl[128];

  int bid = blockIdx.x;                 // 576 = 8 * 72
  int work = (bid & 7) * 72 + (bid >> 3);
  int b = work / 36, rem = work % 36;
  int mt = rem >> 1, nt = rem & 1;
  int mbase = mt * 128, ebase = nt * 128;
  size_t bH = (size_t)b * HW;

  int t = threadIdx.x, lane = t & 63, wv = t >> 6, g4 = lane >> 4, r16 = lane & 15;
  int wr = wv >> 1, wc = wv & 1;        // wave: rows [wr*64,+64), emb [wc*64,+64)

  // inline inv: sum gpart row (16 partials)
  if (t < 128) {
    const float4* pp = (const float4*)(gpart + (bH + mbase + t) * 16);
    float4 p0 = pp[0], p1 = pp[1], p2 = pp[2], p3 = pp[3];
    invl[t] = 1.f / (p0.x+p0.y+p0.z+p0.w + p1.x+p1.y+p1.z+p1.w
                   + p2.x+p2.y+p2.z+p2.w + p3.x+p3.y+p3.z+p3.w);
  }

  const u16* Ebase = (const u16*)(dout + OUT0);
  // staging: 1024 slots each, 4/thread (source pre-swizzled, dest linear)
  int rs[4], cs[4];
  #pragma unroll
  for (int q = 0; q < 4; q++) {
    int idx = q*256 + t;
    rs[q] = idx >> 3;
    cs[q] = (idx & 7) ^ (rs[q] & 7);
  }
  const char* lA = (const char*)lsA;
  const char* lB = (const char*)lsB;

  f32x4 acc[4][4] = {};
  #pragma unroll 1
  for (int ks = 0; ks < 32; ks++) {
    int kb = ks * 64;
    #pragma unroll
    for (int q = 0; q < 4; q++) {
      gload16(Ebase + (bH + mbase + rs[q]) * 4096 + 2048 + kb + cs[q]*8,
              lsA + (q*256 + t)*8);
      gload16(Vtb + ((size_t)b*EMB + ebase + rs[q]) * SEQ + kb + cs[q]*8,
              lsB + (q*256 + t)*8);
    }
    __syncthreads();
    #pragma unroll
    for (int kk = 0; kk < 2; kk++) {
      bf16x8 af[4], bf[4];
      #pragma unroll
      for (int m = 0; m < 4; m++) {
        int row = wr*64 + m*16 + r16;
        af[m] = ld16c(lA + row*128 + (((kk<<2)|g4) ^ (row&7))*16);
      }
      #pragma unroll
      for (int n = 0; n < 4; n++) {
        int row = wc*64 + n*16 + r16;
        bf[n] = ld16c(lB + row*128 + (((kk<<2)|g4) ^ (row&7))*16);
      }
      #pragma unroll
      for (int m = 0; m < 4; m++)
        #pragma unroll
        for (int n = 0; n < 4; n++)
          acc[m][n] = MFMA(af[m], bf[n], acc[m][n]);
    }
    __syncthreads();
  }

  // epilogue: normalize by invl, store O bf16
  #pragma unroll
  for (int m = 0; m < 4; m++)
    #pragma unroll
    for (int r = 0; r < 4; r++) {
      int i = wr*64 + m*16 + g4*4 + r;
      float iv = invl[i];
      #pragma unroll
      for (int n = 0; n < 4; n++) {
        int e = ebase + wc*64 + n*16 + r16;
        Obf[(bH + mbase + i) * 256 + e] = f2bf(acc[m][n][r] * iv);
      }
    }
}

// ---------------- K5: merged att-stream + out-projection (one dispatch) -----
// blocks [0,2304): att = E*inv (destroys E); blocks [2304,2880): out-proj
// (256 active threads). Both depend only on k_pv; fully disjoint data.
__global__ __launch_bounds__(512) void k_tail(
    const float* __restrict__ gpart, float* __restrict__ dout,
    const u16* __restrict__ Obf, const u16* __restrict__ WoutBf,
    const float* __restrict__ bout, float* __restrict__ out)
{
  int bid0 = blockIdx.x;
  if (bid0 < 2304) {
    // ---- att = E * inv, pure streaming (R14 k_att body) ----
    int work = (bid0 & 7) * 288 + (bid0 >> 3);
    int t = threadIdx.x, wv = t >> 6, lane = t & 63;
    #pragma unroll
    for (int rr = 0; rr < 2; rr++) {
      size_t row = (size_t)work * 16 + wv * 2 + rr;
      const u16* Erow = (const u16*)(dout + OUT0) + row * 4096 + 2048;
      float* arow = dout + OUT0 + row * 2048;
      float v = gpart[row * 16 + (lane & 15)];
      v += __shfl_xor(v, 1); v += __shfl_xor(v, 2);
      v += __shfl_xor(v, 4); v += __shfl_xor(v, 8);
      float iv = 1.f / v;
      uint2 raw[8];
      #pragma unroll
      for (int seg = 0; seg < 8; seg++)
        raw[seg] = *(const uint2*)(Erow + (size_t)(seg*64 + lane) * 4);
      asm volatile("s_waitcnt vmcnt(0)" ::: "memory");
      #pragma unroll
      for (int seg = 0; seg < 8; seg++) {
        float4 o;
        o.x = bf2f(raw[seg].x & 0xffffu) * iv;
        o.y = bf2f(raw[seg].x >> 16)     * iv;
        o.z = bf2f(raw[seg].y & 0xffffu) * iv;
        o.w = bf2f(raw[seg].y >> 16)     * iv;
        *(float4*)(arow + (size_t)(seg*64 + lane) * 4) = o;
      }
    }
  } else {
    // ---- out projection (R14 k_outproj body, t<256) ----
    if (threadIdx.x >= 256) return;
    int b2 = bid0 - 2304;               // 0..575
    int b = b2 / 36, ibase = (b2 % 36) * 64;
    int t = threadIdx.x, wv = t >> 6, lane = t & 63, g4 = lane >> 4, r16 = lane & 15;
    int c0 = wv * 64;
    f32x4 acc[4][4] = {};
    #pragma unroll 2
    for (int kk = 0; kk < 8; kk++) {
      bf16x8 a[4];
      #pragma unroll
      for (int m = 0; m < 4; m++)
        a[m] = ld16(WoutBf + (size_t)(c0 + m*16 + r16) * 256 + kk*32 + g4*8);
      bf16x8 bb[4];
      #pragma unroll
      for (int n = 0; n < 4; n++)
        bb[n] = ld16(Obf + ((size_t)b*HW + ibase + n*16 + r16) * EMB + kk*32 + g4*8);
      #pragma unroll
      for (int m = 0; m < 4; m++)
        #pragma unroll
        for (int n = 0; n < 4; n++)
          acc[m][n] = MFMA(a[m], bb[n], acc[m][n]);
    }
    #pragma unroll
    for (int m = 0; m < 4; m++) {
      #pragma unroll
      for (int r = 0; r < 4; r++) {
        int c = c0 + m*16 + g4*4 + r;
        float bo = bout[c];
        #pragma unroll
        for (int n = 0; n < 4; n++) {
          int i = ibase + n*16 + r16;
          out[((size_t)b*CH + c) * HW + i] = acc[m][n][r] + bo;
        }
      }
    }
  }
}

// ---------------- host ------------------------------------------------------
extern "C" void kernel_launch(void* const* d_in, const int* in_sizes, int n_in,
                              void* d_out, int out_size, void* d_ws, size_t ws_size,
                              hipStream_t stream)
{
  const float* x    = (const float*)d_in[0];
  const float* ctx  = (const float*)d_in[1];
  const int*   mask = (const int*)  d_in[2];
  const float* W_in = (const float*)d_in[3];
  const float* b_in = (const float*)d_in[4];
  const float* Wq   = (const float*)d_in[5];
  const float* bq   = (const float*)d_in[6];
  const float* Wk   = (const float*)d_in[7];
  const float* bk   = (const float*)d_in[8];
  const float* Wv   = (const float*)d_in[9];
  const float* bv   = (const float*)d_in[10];
  const float* Wout = (const float*)d_in[11];
  const float* bout = (const float*)d_in[12];
  float* out = (float*)d_out;

  char* ws = (char*)d_ws;
  size_t off = 0;
  auto alloc = [&](size_t bytes) -> void* {
    void* p = ws + off;
    off += (bytes + 255) & ~(size_t)255;
    return p;
  };
  u16*   WqinBf = (u16*)  alloc(256*256*2);
  u16*   WkBf   = (u16*)  alloc(256*128*2);
  u16*   WvBf   = (u16*)  alloc(256*128*2);
  u16*   WoutBf = (u16*)  alloc(256*256*2);
  float* bq_eff = (float*)alloc(256*4);
  float* gpart  = (float*)alloc((size_t)BB*HW*16*4);
  u16*   Qbf    = (u16*)  alloc((size_t)BB*HW*EMB*2);   // reused as O by k_pv
  u16*   Kbf    = (u16*)  alloc((size_t)BB*SEQ*EMB*2);
  u16*   Vtb    = (u16*)  alloc((size_t)BB*EMB*SEQ*2);
  if (off > ws_size) return;  // diagnostic bail

  k_prep<<<dim3(320), dim3(256), 0, stream>>>(Wq, W_in, b_in, bq, Wk, Wv, Wout,
                                              WqinBf, WkBf, WvBf, WoutBf, bq_eff);
  k_proj<<<dim3(1088), dim3(512), 0, stream>>>(x, WqinBf, bq_eff, Qbf,
                                               ctx, WkBf, WvBf, bk, bv, Kbf, Vtb);
  k_qk<<<dim3(4608), dim3(512), 0, stream>>>(Qbf, Kbf, mask, out, gpart);
  k_pv<<<dim3(576), dim3(256), 0, stream>>>(Vtb, gpart, out, Qbf /*O*/);   // BEFORE att!
  k_tail<<<dim3(2880), dim3(512), 0, stream>>>(gpart, out, Qbf /*O*/, WoutBf, bout, out);
}